// Round 3
// baseline (135.366 us; speedup 1.0000x reference)
//
#include <hip/hip_runtime.h>

// ClebschCombiningSingleUnrolled: out[mu] += mult * X1[m1] * X2[m2] (elementwise over N*D)
// M=9 channels, K=100 terms, P = N*D = 1048576 floats per channel.
//
// R3 == R2 (infra failure, never measured): double-buffered streaming pipeline.
// 1-wave blocks, TILE=256 floats, TPB=4 tiles per block. Prefetch next tile via
// global_load_lds, counted s_waitcnt vmcnt(18) so the prefetch stays in flight
// during compute. mu sorted -> static accumulator per segment; runtime m1/m2 ->
// LDS byte offsets from a packed plan in d_ws (prep kernel).

#define M_CH 9
#define TILE 256            // floats per channel per tile (64 lanes x float4)
#define THREADS 64          // one wave per block
#define TPB 4               // tiles per block
#define PLAN_PAD 128

typedef const void __attribute__((address_space(1))) * gcptr;
typedef void       __attribute__((address_space(3))) * lsptr;

__global__ __launch_bounds__(128) void prep_kernel(
    const int* __restrict__ m1, const int* __restrict__ m2,
    const int* __restrict__ mu, const float* __restrict__ mult,
    int K, int* __restrict__ ws) {
    __shared__ int smu[PLAN_PAD];
    int t = threadIdx.x;
    if (t < K) smu[t] = mu[t];
    __syncthreads();
    int4* plan = (int4*)(ws + 16);
    if (t < K) {
        int4 e;
        e.x = m1[t] * (TILE * 4);              // byte offset of X1 channel row in LDS
        e.y = (M_CH + m2[t]) * (TILE * 4);     // byte offset of X2 channel row in LDS
        e.z = __float_as_int(mult[t]);
        e.w = 0;
        plan[t] = e;
    } else if (t < PLAN_PAD) {
        int4 e; e.x = 0; e.y = M_CH * TILE * 4; e.z = 0; e.w = 0;  // mult=0 pad
        plan[t] = e;
    }
    // segment boundaries: seg[m] = #(mu[k] < m); seg[0]=0, seg[9]=K (mu sorted)
    if (t <= M_CH) {
        int c = 0;
        for (int k = 0; k < K; ++k) c += (smu[k] < t) ? 1 : 0;
        ws[t] = c;
    }
}

__device__ __forceinline__ void stage_tile(float* dst, const float* s1,
                                           const float* s2, int P, int tid) {
    // LDS dest = uniform row base + lane*16B (required linear pattern)
    #pragma unroll
    for (int m = 0; m < M_CH; ++m) {
        __builtin_amdgcn_global_load_lds((gcptr)(s1 + m * P),
                                         (lsptr)(dst + m * TILE + tid * 4), 16, 0, 0);
        __builtin_amdgcn_global_load_lds((gcptr)(s2 + m * P),
                                         (lsptr)(dst + (M_CH + m) * TILE + tid * 4), 16, 0, 0);
    }
}

__global__ __launch_bounds__(THREADS) void cleb_kernel(
    const float* __restrict__ X1, const float* __restrict__ X2,
    const int* __restrict__ ws, float* __restrict__ out, int P) {
    __shared__ float lds[2][2 * M_CH * TILE];   // 2 x 18 KB
    const int tid = threadIdx.x;
    const int base0 = blockIdx.x * (TILE * TPB);

    // stage tile 0 into buf 0
    stage_tile(lds[0], X1 + base0 + tid * 4, X2 + base0 + tid * 4, P, tid);

    // uniform plan (scalar loads)
    int seg[M_CH + 1];
    #pragma unroll
    for (int i = 0; i <= M_CH; ++i) seg[i] = ws[i];
    const int4* plan = (const int4*)(ws + 16);
    const int lane_off = tid * 16;

    #pragma unroll
    for (int t = 0; t < TPB; ++t) {
        const int base = base0 + t * TILE;
        if (t + 1 < TPB) {
            // issue next tile's staging BEFORE waiting on current
            stage_tile(lds[(t + 1) & 1], X1 + base + TILE + tid * 4,
                       X2 + base + TILE + tid * 4, P, tid);
            // wait until only the 18 prefetch loads remain -> current buf ready
            asm volatile("s_waitcnt vmcnt(18)" ::: "memory");
        } else {
            asm volatile("s_waitcnt vmcnt(0)" ::: "memory");
        }
        __builtin_amdgcn_sched_barrier(0);

        const char* ldsb = (const char*)lds[t & 1];
        float* outp = out + base + tid * 4;

        #pragma unroll
        for (int m = 0; m < M_CH; ++m) {
            float4 acc = make_float4(0.f, 0.f, 0.f, 0.f);
            const int s_ = seg[m], e_ = seg[m + 1];
            int4 pe = plan[s_];                    // safe: plan padded
            #pragma unroll 4
            for (int k = s_; k < e_; ++k) {
                int4 pn = plan[k + 1];             // prefetch next entry (padded)
                const float4 a = *(const float4*)(ldsb + pe.x + lane_off);
                const float4 b = *(const float4*)(ldsb + pe.y + lane_off);
                const float c = __int_as_float(pe.z);
                acc.x = fmaf(c * a.x, b.x, acc.x);
                acc.y = fmaf(c * a.y, b.y, acc.y);
                acc.z = fmaf(c * a.z, b.z, acc.z);
                acc.w = fmaf(c * a.w, b.w, acc.w);
                pe = pn;
            }
            *(float4*)(outp + m * P) = acc;        // coalesced 16B store
        }
    }
}

extern "C" void kernel_launch(void* const* d_in, const int* in_sizes, int n_in,
                              void* d_out, int out_size, void* d_ws, size_t ws_size,
                              hipStream_t stream) {
    const float* X1   = (const float*)d_in[0];
    const float* X2   = (const float*)d_in[1];
    const int*   m1   = (const int*)d_in[2];
    const int*   m2   = (const int*)d_in[3];
    const int*   mu   = (const int*)d_in[4];
    const float* mult = (const float*)d_in[5];
    float* out = (float*)d_out;
    int*   ws  = (int*)d_ws;

    const int K = in_sizes[2];                 // 100
    const int P = in_sizes[0] / M_CH;          // 1048576

    prep_kernel<<<1, 128, 0, stream>>>(m1, m2, mu, mult, K, ws);
    cleb_kernel<<<P / (TILE * TPB), THREADS, 0, stream>>>(X1, X2, ws, out, P);
}